// Round 1
// baseline (126.546 us; speedup 1.0000x reference)
//
#include <hip/hip_runtime.h>

#define DIM 192

// nearest-resample index map for pass 1 (mid index t -> vol index),
// bit-exact with: clip(round(clip(t / dz, 0, 192)), 0, 191)
__device__ __forceinline__ int nearest_map(int t, float dz) {
    float dl = (float)t / dz;                 // same float div as jnp
    dl = fminf(fmaxf(dl, 0.0f), 192.0f);      // layer clip to [0, inshape]
    float r = rintf(dl);                      // round half-to-even == jnp.round
    r = fminf(r, 191.0f);                     // interp_nearest clip
    return (int)r;
}

__global__ __launch_bounds__(256) void mimic_acq_kernel(
    const float* __restrict__ vol,    // [2,192,192,192,1]
    const float* __restrict__ sres,   // [2,3]
    float* __restrict__ out)          // [2,192,192,192,1]
{
    const int z  = blockIdx.x * 64 + threadIdx.x;   // block (64,4,1)
    const int y  = blockIdx.y * 4  + threadIdx.y;
    const int bx = blockIdx.z;                      // b*192 + x
    const int b  = (bx >= DIM) ? 1 : 0;
    const int x  = bx - b * DIM;

    // per-example down_shape = int32(192.0 * 1.0 / sr)  (truncation)
    const float srx = sres[b * 3 + 0];
    const float sry = sres[b * 3 + 1];
    const float srz = sres[b * 3 + 2];
    const int dsx = (int)(192.0f / srx);
    const int dsy = (int)(192.0f / sry);
    const int dsz = (int)(192.0f / srz);
    const float dsxf = (float)dsx, dsyf = (float)dsy, dszf = (float)dsz;

    // ---- pass 2 (trilinear) coordinates on the mid grid ----
    // up_loc = i / (192/ds)  -- replicate exact op order
    const float uzx = 192.0f / dsxf;
    const float uzy = 192.0f / dsyf;
    const float uzz = 192.0f / dszf;

    float lx = (float)x / uzx; lx = fminf(fmaxf(lx, 0.0f), 191.0f);
    float ly = (float)y / uzy; ly = fminf(fmaxf(ly, 0.0f), 191.0f);
    float lz = (float)z / uzz; lz = fminf(fmaxf(lz, 0.0f), 191.0f);

    const float f0x = floorf(lx), f0y = floorf(ly), f0z = floorf(lz);
    const float f1x = fminf(f0x + 1.0f, 191.0f);
    const float f1y = fminf(f0y + 1.0f, 191.0f);
    const float f1z = fminf(f0z + 1.0f, 191.0f);

    const float w0x = f1x - lx, w1x = 1.0f - w0x;
    const float w0y = f1y - ly, w1y = 1.0f - w0y;
    const float w0z = f1z - lz, w1z = 1.0f - w0z;

    const int i0x = (int)f0x, i1x = (int)f1x;
    const int i0y = (int)f0y, i1y = (int)f1y;
    const int i0z = (int)f0z, i1z = (int)f1z;

    // ---- pass 1 (nearest) index maps, fused ----
    const float dzx = dsxf / 192.0f;
    const float dzy = dsyf / 192.0f;
    const float dzz = dszf / 192.0f;

    const int nx0 = nearest_map(i0x, dzx), nx1 = nearest_map(i1x, dzx);
    const int ny0 = nearest_map(i0y, dzy), ny1 = nearest_map(i1y, dzy);
    const int nz0 = nearest_map(i0z, dzz), nz1 = nearest_map(i1z, dzz);

    const float* vb = vol + (size_t)b * (DIM * DIM * DIM);

    // 8-corner weighted sum, same corner order / weight multiply order as ref
    float acc = 0.0f;
#pragma unroll
    for (int c = 0; c < 8; ++c) {
        const int xi = (c & 1) ? nx1 : nx0;
        const int yi = (c & 2) ? ny1 : ny0;
        const int zi = (c & 4) ? nz1 : nz0;
        const float w = ((c & 1) ? w1x : w0x)
                      * ((c & 2) ? w1y : w0y)
                      * ((c & 4) ? w1z : w0z);
        acc += w * vb[((size_t)xi * DIM + yi) * DIM + zi];
    }

    out[((size_t)bx * DIM + y) * DIM + z] = acc;
}

extern "C" void kernel_launch(void* const* d_in, const int* in_sizes, int n_in,
                              void* d_out, int out_size, void* d_ws, size_t ws_size,
                              hipStream_t stream) {
    const float* vol  = (const float*)d_in[0];
    const float* sres = (const float*)d_in[1];
    float* out = (float*)d_out;

    dim3 block(64, 4, 1);
    dim3 grid(DIM / 64, DIM / 4, 2 * DIM);  // (3, 48, 384)
    hipLaunchKernelGGL(mimic_acq_kernel, grid, block, 0, stream, vol, sres, out);
}

// Round 2
// 53.087 us; speedup vs baseline: 2.3838x; 2.3838x over previous
//
#include <hip/hip_runtime.h>

#define DIM 192

// nearest-resample index map for pass 1 (mid index t -> vol index),
// bit-exact with: clip(round(clip(t / dz, 0, 192)), 0, 191)
__device__ __forceinline__ int nearest_map(int t, float dz) {
    float dl = (float)t / dz;                 // same float div as jnp
    dl = fminf(fmaxf(dl, 0.0f), 192.0f);      // layer clip to [0, inshape]
    float r = rintf(dl);                      // round half-to-even == jnp.round
    r = fminf(r, 191.0f);                     // interp_nearest clip
    return (int)r;
}

// ---- Kernel 1: per-(batch,axis,i) LUT: {w0, w1, nearest(i0), nearest(i1)} ----
// 2 batches * 3 axes * 192 coords = 1152 entries, 16 B each.
__global__ __launch_bounds__(192) void build_lut_kernel(
    const float* __restrict__ sres,   // [2,3]
    float4* __restrict__ lut)         // [2*3*192]
{
    const int e = blockIdx.x * 192 + threadIdx.x;   // e in [0, 1152)
    if (e >= 2 * 3 * DIM) return;
    const int i  = e % DIM;
    const int ba = e / DIM;            // b*3 + axis

    const float sr = sres[ba];
    const int   ds = (int)(192.0f / sr);     // int32 truncation, as astype
    const float dsf = (float)ds;

    // pass-2 trilinear coordinate (exact op order of reference)
    const float uz = 192.0f / dsf;
    float l = (float)i / uz;
    l = fminf(fmaxf(l, 0.0f), 191.0f);
    const float f0 = floorf(l);
    const float f1 = fminf(f0 + 1.0f, 191.0f);
    const float w0 = f1 - l;
    const float w1 = 1.0f - w0;

    // pass-1 nearest map applied to both corners
    const float dz = dsf / 192.0f;
    const int n0 = nearest_map((int)f0, dz);
    const int n1 = nearest_map((int)f1, dz);

    float4 v;
    v.x = w0;
    v.y = w1;
    v.z = __int_as_float(n0);
    v.w = __int_as_float(n1);
    lut[e] = v;
}

// ---- Kernel 2: 3 LUT loads + 8 gathers + weighted sum ----
__global__ __launch_bounds__(256) void mimic_acq_lut_kernel(
    const float* __restrict__ vol,    // [2,192,192,192,1]
    const float4* __restrict__ lut,   // [2*3*192]
    float* __restrict__ out)          // [2,192,192,192,1]
{
    const int z  = blockIdx.x * 64 + threadIdx.x;   // block (64,4,1)
    const int y  = blockIdx.y * 4  + threadIdx.y;
    const int bx = blockIdx.z;                      // b*192 + x
    const int b  = (bx >= DIM) ? 1 : 0;
    const int x  = bx - b * DIM;

    const float4 ex = lut[(b * 3 + 0) * DIM + x];
    const float4 ey = lut[(b * 3 + 1) * DIM + y];
    const float4 ez = lut[(b * 3 + 2) * DIM + z];

    const float w0x = ex.x, w1x = ex.y;
    const float w0y = ey.x, w1y = ey.y;
    const float w0z = ez.x, w1z = ez.y;
    const int nx0 = __float_as_int(ex.z), nx1 = __float_as_int(ex.w);
    const int ny0 = __float_as_int(ey.z), ny1 = __float_as_int(ey.w);
    const int nz0 = __float_as_int(ez.z), nz1 = __float_as_int(ez.w);

    const float* vb = vol + (size_t)b * (DIM * DIM * DIM);

    const int base00 = (nx0 * DIM + ny0) * DIM;
    const int base01 = (nx0 * DIM + ny1) * DIM;
    const int base10 = (nx1 * DIM + ny0) * DIM;
    const int base11 = (nx1 * DIM + ny1) * DIM;

    // corner order and weight-multiply order identical to reference
    const float v000 = vb[base00 + nz0];
    const float v100 = vb[base10 + nz0];
    const float v010 = vb[base01 + nz0];
    const float v110 = vb[base11 + nz0];
    const float v001 = vb[base00 + nz1];
    const float v101 = vb[base10 + nz1];
    const float v011 = vb[base01 + nz1];
    const float v111 = vb[base11 + nz1];

    float acc = 0.0f;
    acc += (w0x * w0y) * w0z * v000;
    acc += (w1x * w0y) * w0z * v100;
    acc += (w0x * w1y) * w0z * v010;
    acc += (w1x * w1y) * w0z * v110;
    acc += (w0x * w0y) * w1z * v001;
    acc += (w1x * w0y) * w1z * v101;
    acc += (w0x * w1y) * w1z * v011;
    acc += (w1x * w1y) * w1z * v111;

    __builtin_nontemporal_store(acc, &out[((size_t)bx * DIM + y) * DIM + z]);
}

// Fallback (round-1 kernel) in case ws is too small for the LUT.
__global__ __launch_bounds__(256) void mimic_acq_fused_kernel(
    const float* __restrict__ vol,
    const float* __restrict__ sres,
    float* __restrict__ out)
{
    const int z  = blockIdx.x * 64 + threadIdx.x;
    const int y  = blockIdx.y * 4  + threadIdx.y;
    const int bx = blockIdx.z;
    const int b  = (bx >= DIM) ? 1 : 0;
    const int x  = bx - b * DIM;

    const float srx = sres[b * 3 + 0];
    const float sry = sres[b * 3 + 1];
    const float srz = sres[b * 3 + 2];
    const int dsx = (int)(192.0f / srx);
    const int dsy = (int)(192.0f / sry);
    const int dsz = (int)(192.0f / srz);
    const float dsxf = (float)dsx, dsyf = (float)dsy, dszf = (float)dsz;

    const float uzx = 192.0f / dsxf;
    const float uzy = 192.0f / dsyf;
    const float uzz = 192.0f / dszf;

    float lx = (float)x / uzx; lx = fminf(fmaxf(lx, 0.0f), 191.0f);
    float ly = (float)y / uzy; ly = fminf(fmaxf(ly, 0.0f), 191.0f);
    float lz = (float)z / uzz; lz = fminf(fmaxf(lz, 0.0f), 191.0f);

    const float f0x = floorf(lx), f0y = floorf(ly), f0z = floorf(lz);
    const float f1x = fminf(f0x + 1.0f, 191.0f);
    const float f1y = fminf(f0y + 1.0f, 191.0f);
    const float f1z = fminf(f0z + 1.0f, 191.0f);

    const float w0x = f1x - lx, w1x = 1.0f - w0x;
    const float w0y = f1y - ly, w1y = 1.0f - w0y;
    const float w0z = f1z - lz, w1z = 1.0f - w0z;

    const float dzx = dsxf / 192.0f;
    const float dzy = dsyf / 192.0f;
    const float dzz = dszf / 192.0f;

    const int nx0 = nearest_map((int)f0x, dzx), nx1 = nearest_map((int)f1x, dzx);
    const int ny0 = nearest_map((int)f0y, dzy), ny1 = nearest_map((int)f1y, dzy);
    const int nz0 = nearest_map((int)f0z, dzz), nz1 = nearest_map((int)f1z, dzz);

    const float* vb = vol + (size_t)b * (DIM * DIM * DIM);

    float acc = 0.0f;
#pragma unroll
    for (int c = 0; c < 8; ++c) {
        const int xi = (c & 1) ? nx1 : nx0;
        const int yi = (c & 2) ? ny1 : ny0;
        const int zi = (c & 4) ? nz1 : nz0;
        const float w = ((c & 1) ? w1x : w0x)
                      * ((c & 2) ? w1y : w0y)
                      * ((c & 4) ? w1z : w0z);
        acc += w * vb[((size_t)xi * DIM + yi) * DIM + zi];
    }

    out[((size_t)bx * DIM + y) * DIM + z] = acc;
}

extern "C" void kernel_launch(void* const* d_in, const int* in_sizes, int n_in,
                              void* d_out, int out_size, void* d_ws, size_t ws_size,
                              hipStream_t stream) {
    const float* vol  = (const float*)d_in[0];
    const float* sres = (const float*)d_in[1];
    float* out = (float*)d_out;

    const size_t lut_bytes = (size_t)2 * 3 * DIM * sizeof(float4);

    dim3 block(64, 4, 1);
    dim3 grid(DIM / 64, DIM / 4, 2 * DIM);  // (3, 48, 384)

    if (ws_size >= lut_bytes) {
        float4* lut = (float4*)d_ws;
        hipLaunchKernelGGL(build_lut_kernel, dim3(6), dim3(192), 0, stream, sres, lut);
        hipLaunchKernelGGL(mimic_acq_lut_kernel, grid, block, 0, stream, vol, lut, out);
    } else {
        hipLaunchKernelGGL(mimic_acq_fused_kernel, grid, block, 0, stream, vol, sres, out);
    }
}

// Round 3
// 42.755 us; speedup vs baseline: 2.9598x; 1.2416x over previous
//
#include <hip/hip_runtime.h>

#define DIM 192

// nearest-resample index map for pass 1 (mid index t -> vol index),
// bit-exact with: clip(round(clip(t / dz, 0, 192)), 0, 191)
__device__ __forceinline__ int nearest_map(int t, float dz) {
    float dl = (float)t / dz;                 // same float div as jnp
    dl = fminf(fmaxf(dl, 0.0f), 192.0f);      // layer clip to [0, inshape]
    float r = rintf(dl);                      // round half-to-even == jnp.round
    r = fminf(r, 191.0f);                     // interp_nearest clip
    return (int)r;
}

// ws layout: lutx float4[2*192] @ 0 ; luty float4[2*192] @ 6144 B ; lutz float2[2*192] @ 12288 B
#define LUTX_OFF 0
#define LUTY_OFF (2 * DIM)            // in float4 units
#define LUTZ_OFF (4 * DIM)            // in float4 units (lutz uses float2, aliased)

// ---- Kernel 1: per-(batch,axis,i) LUTs with pre-scaled row offsets ----
__global__ __launch_bounds__(192) void build_lut_kernel(
    const float* __restrict__ sres,   // [2,3]
    float4* __restrict__ ws)
{
    const int e = blockIdx.x * 192 + threadIdx.x;   // e in [0, 1152)
    if (e >= 2 * 3 * DIM) return;
    const int i  = e % DIM;
    const int ba = e / DIM;            // b*3 + axis
    const int b  = ba / 3;
    const int ax = ba % 3;

    const float sr = sres[ba];
    const int   ds = (int)(192.0f / sr);     // int32 truncation, as astype
    const float dsf = (float)ds;

    // pass-2 trilinear coordinate (exact op order of reference)
    const float uz = 192.0f / dsf;
    float l = (float)i / uz;
    l = fminf(fmaxf(l, 0.0f), 191.0f);
    const float f0 = floorf(l);
    const float f1 = fminf(f0 + 1.0f, 191.0f);
    const float w0 = f1 - l;

    // pass-1 nearest map applied to both corners
    const float dz = dsf / 192.0f;
    const int n0 = nearest_map((int)f0, dz);
    const int n1 = nearest_map((int)f1, dz);

    if (ax == 0) {
        float4 v;
        v.x = w0;
        v.y = __int_as_float(n0 * (DIM * DIM));
        v.z = __int_as_float(n1 * (DIM * DIM));
        v.w = 0.0f;
        ws[LUTX_OFF + b * DIM + i] = v;
    } else if (ax == 1) {
        float4 v;
        v.x = w0;
        v.y = __int_as_float(n0 * DIM);
        v.z = __int_as_float(n1 * DIM);
        v.w = 0.0f;
        ws[LUTY_OFF + b * DIM + i] = v;
    } else {
        float2 v;
        v.x = w0;
        v.y = __int_as_float(n0 | (n1 << 16));
        ((float2*)(ws + LUTZ_OFF))[b * DIM + i] = v;
    }
}

// ---- Kernel 2: 4 y-outputs per thread ----
__global__ __launch_bounds__(256) void mimic_acq_lut4_kernel(
    const float* __restrict__ vol,    // [2,192,192,192,1]
    const float4* __restrict__ ws,
    float* __restrict__ out)          // [2,192,192,192,1]
{
    const int z  = blockIdx.x * 64 + threadIdx.x;           // block (64,4,1)
    const int y0 = blockIdx.y * 16 + threadIdx.y * 4;       // 4 consecutive y
    const int bx = blockIdx.z;                              // b*192 + x
    const int b  = (bx >= DIM) ? 1 : 0;
    const int x  = bx - b * DIM;

    // x entry: wave-uniform (depends only on blockIdx.z)
    const float4 ex = ws[LUTX_OFF + b * DIM + x];
    const float w0x = ex.x, w1x = 1.0f - ex.x;
    const int ox0 = __float_as_int(ex.y), ox1 = __float_as_int(ex.z);

    // z entry: lane-varying, 8 B packed
    const float2 ez = ((const float2*)(ws + LUTZ_OFF))[b * DIM + z];
    const float w0z = ez.x, w1z = 1.0f - ez.x;
    const int pkz = __float_as_int(ez.y);
    const int nz0 = pkz & 0xffff, nz1 = pkz >> 16;

    const float* vb = vol + (size_t)b * (DIM * DIM * DIM);
    float* ob = out + ((size_t)bx * DIM + y0) * DIM + z;

#pragma unroll
    for (int j = 0; j < 4; ++j) {
        const float4 ey = ws[LUTY_OFF + b * DIM + y0 + j];
        const float w0y = ey.x, w1y = 1.0f - ey.x;
        const int oy0 = __float_as_int(ey.y), oy1 = __float_as_int(ey.z);

        const int r00 = ox0 + oy0;
        const int r01 = ox0 + oy1;
        const int r10 = ox1 + oy0;
        const int r11 = ox1 + oy1;

        const float v000 = vb[r00 + nz0];
        const float v100 = vb[r10 + nz0];
        const float v010 = vb[r01 + nz0];
        const float v110 = vb[r11 + nz0];
        const float v001 = vb[r00 + nz1];
        const float v101 = vb[r10 + nz1];
        const float v011 = vb[r01 + nz1];
        const float v111 = vb[r11 + nz1];

        // same association order as the passing kernel: (wx*wy)*wz
        const float a00 = w0x * w0y;
        const float a10 = w1x * w0y;
        const float a01 = w0x * w1y;
        const float a11 = w1x * w1y;

        float acc = 0.0f;
        acc += a00 * w0z * v000;
        acc += a10 * w0z * v100;
        acc += a01 * w0z * v010;
        acc += a11 * w0z * v110;
        acc += a00 * w1z * v001;
        acc += a10 * w1z * v101;
        acc += a01 * w1z * v011;
        acc += a11 * w1z * v111;

        __builtin_nontemporal_store(acc, ob + (size_t)j * DIM);
    }
}

// Fallback (round-1 kernel) in case ws is too small for the LUT.
__global__ __launch_bounds__(256) void mimic_acq_fused_kernel(
    const float* __restrict__ vol,
    const float* __restrict__ sres,
    float* __restrict__ out)
{
    const int z  = blockIdx.x * 64 + threadIdx.x;
    const int y  = blockIdx.y * 4  + threadIdx.y;
    const int bx = blockIdx.z;
    const int b  = (bx >= DIM) ? 1 : 0;
    const int x  = bx - b * DIM;

    const float srx = sres[b * 3 + 0];
    const float sry = sres[b * 3 + 1];
    const float srz = sres[b * 3 + 2];
    const int dsx = (int)(192.0f / srx);
    const int dsy = (int)(192.0f / sry);
    const int dsz = (int)(192.0f / srz);
    const float dsxf = (float)dsx, dsyf = (float)dsy, dszf = (float)dsz;

    const float uzx = 192.0f / dsxf;
    const float uzy = 192.0f / dsyf;
    const float uzz = 192.0f / dszf;

    float lx = (float)x / uzx; lx = fminf(fmaxf(lx, 0.0f), 191.0f);
    float ly = (float)y / uzy; ly = fminf(fmaxf(ly, 0.0f), 191.0f);
    float lz = (float)z / uzz; lz = fminf(fmaxf(lz, 0.0f), 191.0f);

    const float f0x = floorf(lx), f0y = floorf(ly), f0z = floorf(lz);
    const float f1x = fminf(f0x + 1.0f, 191.0f);
    const float f1y = fminf(f0y + 1.0f, 191.0f);
    const float f1z = fminf(f0z + 1.0f, 191.0f);

    const float w0x = f1x - lx, w1x = 1.0f - w0x;
    const float w0y = f1y - ly, w1y = 1.0f - w0y;
    const float w0z = f1z - lz, w1z = 1.0f - w0z;

    const float dzx = dsxf / 192.0f;
    const float dzy = dsyf / 192.0f;
    const float dzz = dszf / 192.0f;

    const int nx0 = nearest_map((int)f0x, dzx), nx1 = nearest_map((int)f1x, dzx);
    const int ny0 = nearest_map((int)f0y, dzy), ny1 = nearest_map((int)f1y, dzy);
    const int nz0 = nearest_map((int)f0z, dzz), nz1 = nearest_map((int)f1z, dzz);

    const float* vb = vol + (size_t)b * (DIM * DIM * DIM);

    float acc = 0.0f;
#pragma unroll
    for (int c = 0; c < 8; ++c) {
        const int xi = (c & 1) ? nx1 : nx0;
        const int yi = (c & 2) ? ny1 : ny0;
        const int zi = (c & 4) ? nz1 : nz0;
        const float w = ((c & 1) ? w1x : w0x)
                      * ((c & 2) ? w1y : w0y)
                      * ((c & 4) ? w1z : w0z);
        acc += w * vb[((size_t)xi * DIM + yi) * DIM + zi];
    }

    out[((size_t)bx * DIM + y) * DIM + z] = acc;
}

extern "C" void kernel_launch(void* const* d_in, const int* in_sizes, int n_in,
                              void* d_out, int out_size, void* d_ws, size_t ws_size,
                              hipStream_t stream) {
    const float* vol  = (const float*)d_in[0];
    const float* sres = (const float*)d_in[1];
    float* out = (float*)d_out;

    const size_t lut_bytes = (size_t)(4 * DIM) * sizeof(float4) + (size_t)(2 * DIM) * sizeof(float2);

    if (ws_size >= lut_bytes) {
        float4* ws = (float4*)d_ws;
        hipLaunchKernelGGL(build_lut_kernel, dim3(6), dim3(192), 0, stream, sres, ws);
        dim3 block(64, 4, 1);
        dim3 grid(DIM / 64, DIM / 16, 2 * DIM);  // (3, 12, 384)
        hipLaunchKernelGGL(mimic_acq_lut4_kernel, grid, block, 0, stream, vol, ws, out);
    } else {
        dim3 block(64, 4, 1);
        dim3 grid(DIM / 64, DIM / 4, 2 * DIM);  // (3, 48, 384)
        hipLaunchKernelGGL(mimic_acq_fused_kernel, grid, block, 0, stream, vol, sres, out);
    }
}

// Round 4
// 40.031 us; speedup vs baseline: 3.1612x; 1.0681x over previous
//
#include <hip/hip_runtime.h>

#define DIM 192
#define RMAX 26   // max staged y-rows: span <= 16 + 2*(192/ds) + 1 <= 25 for ds>=48 (sr<4)

// nearest-resample index map for pass 1 (mid index t -> vol index),
// bit-exact with: clip(round(clip(t / dz, 0, 192)), 0, 191)
__device__ __forceinline__ int nearest_map(int t, float dz) {
    float dl = (float)t / dz;                 // same float div as jnp
    dl = fminf(fmaxf(dl, 0.0f), 192.0f);      // layer clip to [0, inshape]
    float r = rintf(dl);                      // round half-to-even == jnp.round
    r = fminf(r, 191.0f);                     // interp_nearest clip
    return (int)r;
}

// ---- Kernel 1: per-(batch,axis,i) LUT: {w0, n0, n1} (raw indices) ----
__global__ __launch_bounds__(192) void build_lut_kernel(
    const float* __restrict__ sres,   // [2,3]
    float4* __restrict__ lut)         // [2*3*192]
{
    const int e = blockIdx.x * 192 + threadIdx.x;   // e in [0, 1152)
    if (e >= 2 * 3 * DIM) return;
    const int i  = e % DIM;
    const int ba = e / DIM;            // b*3 + axis

    const float sr = sres[ba];
    const int   ds = (int)(192.0f / sr);     // int32 truncation, as astype
    const float dsf = (float)ds;

    // pass-2 trilinear coordinate (exact op order of reference)
    const float uz = 192.0f / dsf;
    float l = (float)i / uz;
    l = fminf(fmaxf(l, 0.0f), 191.0f);
    const float f0 = floorf(l);
    const float f1 = fminf(f0 + 1.0f, 191.0f);
    const float w0 = f1 - l;

    // pass-1 nearest map applied to both corners
    const float dz = dsf / 192.0f;
    const int n0 = nearest_map((int)f0, dz);
    const int n1 = nearest_map((int)f1, dz);

    float4 v;
    v.x = w0;
    v.y = __int_as_float(n0);
    v.z = __int_as_float(n1);
    v.w = 0.0f;
    lut[e] = v;
}

// ---- Kernel 2: LDS-staged fused resample ----
// Block: one (b,x) output slice row-group: 16 y x 192 z. Threads (64,4).
// Stage vol[x0/x1][nymin..nymax][0..191] into LDS as [R][2][192] floats,
// then 8 ds_read per output.
__global__ __launch_bounds__(256) void mimic_acq_lds_kernel(
    const float* __restrict__ vol,    // [2,192,192,192,1]
    const float4* __restrict__ lut,   // [2*3*192]
    float* __restrict__ out)          // [2,192,192,192,1]
{
    __shared__ float lds[RMAX * 2 * DIM];   // 39936 B -> 4 blocks/CU

    const int tz  = threadIdx.x;            // 0..63  (z lane)
    const int ty  = threadIdx.y;            // 0..3
    const int tid = ty * 64 + tz;
    const int ytile = blockIdx.x;           // 0..11
    const int bx    = blockIdx.y;           // b*192 + x
    const int b  = (bx >= DIM) ? 1 : 0;
    const int x  = bx - b * DIM;
    const int y0t = ytile * 16;

    // x corners (wave-uniform)
    const float4 ex = lut[(b * 3 + 0) * DIM + x];
    const float w0x = ex.x, w1x = 1.0f - ex.x;
    const int nx0 = __float_as_int(ex.y), nx1 = __float_as_int(ex.z);

    // y staging range: n0/n1 monotone in y -> [n0(first), n1(last)]
    const float4 eyf = lut[(b * 3 + 1) * DIM + y0t];
    const float4 eyl = lut[(b * 3 + 1) * DIM + y0t + 15];
    const int nymin = __float_as_int(eyf.y);
    const int nymax = __float_as_int(eyl.z);
    const int R = nymax - nymin + 1;        // <= 25 for sr in [1,4)

    const float* vb = vol + (size_t)b * (DIM * DIM * DIM);

    // ---- stage: LDS float4 index c == (y*2+xi)*48 + z4, c in [0, R*96) ----
    const int C = R * 96;
    for (int c = tid; c < C; c += 256) {
        const int y  = c / 96;              // const-divide
        const int r  = c - y * 96;
        const int xi = (r >= 48) ? 1 : 0;
        const int z4 = r - xi * 48;
        const int gx = xi ? nx1 : nx0;
        const float4 v = *(const float4*)(vb + ((size_t)gx * DIM + (nymin + y)) * DIM + z4 * 4);
        ((float4*)lds)[c] = v;
    }
    __syncthreads();

    // z LUT entries for this lane's 3 z positions
    float w0z[3];
    int   o0[3], o1[3];
#pragma unroll
    for (int k = 0; k < 3; ++k) {
        const int z = tz + k * 64;
        const float4 ez = lut[(b * 3 + 2) * DIM + z];
        w0z[k] = ez.x;
        o0[k]  = __float_as_int(ez.y);      // raw nz0
        o1[k]  = __float_as_int(ez.z);      // raw nz1
    }

#pragma unroll
    for (int yj = 0; yj < 4; ++yj) {
        const int y = y0t + ty * 4 + yj;
        const float4 ey = lut[(b * 3 + 1) * DIM + y];
        const float w0y = ey.x, w1y = 1.0f - ey.x;
        const int ny0 = __float_as_int(ey.y), ny1 = __float_as_int(ey.z);

        const int b00 = ((ny0 - nymin) * 2    ) * DIM;
        const int b10 = ((ny0 - nymin) * 2 + 1) * DIM;
        const int b01 = ((ny1 - nymin) * 2    ) * DIM;
        const int b11 = ((ny1 - nymin) * 2 + 1) * DIM;

        const float a00 = w0x * w0y;
        const float a10 = w1x * w0y;
        const float a01 = w0x * w1y;
        const float a11 = w1x * w1y;

        float* ob = out + ((size_t)bx * DIM + y) * DIM;

#pragma unroll
        for (int k = 0; k < 3; ++k) {
            const float v000 = lds[b00 + o0[k]];
            const float v100 = lds[b10 + o0[k]];
            const float v010 = lds[b01 + o0[k]];
            const float v110 = lds[b11 + o0[k]];
            const float v001 = lds[b00 + o1[k]];
            const float v101 = lds[b10 + o1[k]];
            const float v011 = lds[b01 + o1[k]];
            const float v111 = lds[b11 + o1[k]];

            const float wz0 = w0z[k];
            const float wz1 = 1.0f - wz0;

            // identical association order to the passing kernel: (a)*(wz)*v
            float acc = 0.0f;
            acc += a00 * wz0 * v000;
            acc += a10 * wz0 * v100;
            acc += a01 * wz0 * v010;
            acc += a11 * wz0 * v110;
            acc += a00 * wz1 * v001;
            acc += a10 * wz1 * v101;
            acc += a01 * wz1 * v011;
            acc += a11 * wz1 * v111;

            __builtin_nontemporal_store(acc, ob + tz + k * 64);
        }
    }
}

// Fallback (round-1 kernel) in case ws is too small for the LUT.
__global__ __launch_bounds__(256) void mimic_acq_fused_kernel(
    const float* __restrict__ vol,
    const float* __restrict__ sres,
    float* __restrict__ out)
{
    const int z  = blockIdx.x * 64 + threadIdx.x;
    const int y  = blockIdx.y * 4  + threadIdx.y;
    const int bx = blockIdx.z;
    const int b  = (bx >= DIM) ? 1 : 0;
    const int x  = bx - b * DIM;

    const float srx = sres[b * 3 + 0];
    const float sry = sres[b * 3 + 1];
    const float srz = sres[b * 3 + 2];
    const int dsx = (int)(192.0f / srx);
    const int dsy = (int)(192.0f / sry);
    const int dsz = (int)(192.0f / srz);
    const float dsxf = (float)dsx, dsyf = (float)dsy, dszf = (float)dsz;

    const float uzx = 192.0f / dsxf;
    const float uzy = 192.0f / dsyf;
    const float uzz = 192.0f / dszf;

    float lx = (float)x / uzx; lx = fminf(fmaxf(lx, 0.0f), 191.0f);
    float ly = (float)y / uzy; ly = fminf(fmaxf(ly, 0.0f), 191.0f);
    float lz = (float)z / uzz; lz = fminf(fmaxf(lz, 0.0f), 191.0f);

    const float f0x = floorf(lx), f0y = floorf(ly), f0z = floorf(lz);
    const float f1x = fminf(f0x + 1.0f, 191.0f);
    const float f1y = fminf(f0y + 1.0f, 191.0f);
    const float f1z = fminf(f0z + 1.0f, 191.0f);

    const float w0x = f1x - lx, w1x = 1.0f - w0x;
    const float w0y = f1y - ly, w1y = 1.0f - w0y;
    const float w0z = f1z - lz, w1z = 1.0f - w0z;

    const float dzx = dsxf / 192.0f;
    const float dzy = dsyf / 192.0f;
    const float dzz = dszf / 192.0f;

    const int nx0 = nearest_map((int)f0x, dzx), nx1 = nearest_map((int)f1x, dzx);
    const int ny0 = nearest_map((int)f0y, dzy), ny1 = nearest_map((int)f1y, dzy);
    const int nz0 = nearest_map((int)f0z, dzz), nz1 = nearest_map((int)f1z, dzz);

    const float* vb = vol + (size_t)b * (DIM * DIM * DIM);

    float acc = 0.0f;
#pragma unroll
    for (int c = 0; c < 8; ++c) {
        const int xi = (c & 1) ? nx1 : nx0;
        const int yi = (c & 2) ? ny1 : ny0;
        const int zi = (c & 4) ? nz1 : nz0;
        const float w = ((c & 1) ? w1x : w0x)
                      * ((c & 2) ? w1y : w0y)
                      * ((c & 4) ? w1z : w0z);
        acc += w * vb[((size_t)xi * DIM + yi) * DIM + zi];
    }

    out[((size_t)bx * DIM + y) * DIM + z] = acc;
}

extern "C" void kernel_launch(void* const* d_in, const int* in_sizes, int n_in,
                              void* d_out, int out_size, void* d_ws, size_t ws_size,
                              hipStream_t stream) {
    const float* vol  = (const float*)d_in[0];
    const float* sres = (const float*)d_in[1];
    float* out = (float*)d_out;

    const size_t lut_bytes = (size_t)(2 * 3 * DIM) * sizeof(float4);

    if (ws_size >= lut_bytes) {
        float4* lut = (float4*)d_ws;
        hipLaunchKernelGGL(build_lut_kernel, dim3(6), dim3(192), 0, stream, sres, lut);
        dim3 block(64, 4, 1);
        dim3 grid(12, 2 * DIM, 1);   // (ytile, b*192+x)
        hipLaunchKernelGGL(mimic_acq_lds_kernel, grid, block, 0, stream, vol, lut, out);
    } else {
        dim3 block(64, 4, 1);
        dim3 grid(DIM / 64, DIM / 4, 2 * DIM);
        hipLaunchKernelGGL(mimic_acq_fused_kernel, grid, block, 0, stream, vol, sres, out);
    }
}

// Round 5
// 37.220 us; speedup vs baseline: 3.3999x; 1.0755x over previous
//
#include <hip/hip_runtime.h>

#define DIM 192
#define RMAX 26   // max staged y-rows: span <= 15 + 2*(192/ds) + 1 <= 24 for ds>=48 (sr<4)

// nearest-resample index map for pass 1 (mid index t -> vol index),
// bit-exact with: clip(round(clip(t / dz, 0, 192)), 0, 191)
__device__ __forceinline__ int nearest_map(int t, float dz) {
    float dl = (float)t / dz;                 // same float div as jnp
    dl = fminf(fmaxf(dl, 0.0f), 192.0f);      // layer clip to [0, inshape]
    float r = rintf(dl);                      // round half-to-even == jnp.round
    r = fminf(r, 191.0f);                     // interp_nearest clip
    return (int)r;
}

// ---- Kernel 1: per-(batch,axis,i) LUT: {w0, n0, n1} (raw indices) ----
__global__ __launch_bounds__(192) void build_lut_kernel(
    const float* __restrict__ sres,   // [2,3]
    float4* __restrict__ lut)         // [2*3*192]
{
    const int e = blockIdx.x * 192 + threadIdx.x;   // e in [0, 1152)
    if (e >= 2 * 3 * DIM) return;
    const int i  = e % DIM;
    const int ba = e / DIM;            // b*3 + axis

    const float sr = sres[ba];
    const int   ds = (int)(192.0f / sr);     // int32 truncation, as astype
    const float dsf = (float)ds;

    // pass-2 trilinear coordinate (exact op order of reference)
    const float uz = 192.0f / dsf;
    float l = (float)i / uz;
    l = fminf(fmaxf(l, 0.0f), 191.0f);
    const float f0 = floorf(l);
    const float f1 = fminf(f0 + 1.0f, 191.0f);
    const float w0 = f1 - l;

    // pass-1 nearest map applied to both corners
    const float dz = dsf / 192.0f;
    const int n0 = nearest_map((int)f0, dz);
    const int n1 = nearest_map((int)f1, dz);

    float4 v;
    v.x = w0;
    v.y = __int_as_float(n0);
    v.z = __int_as_float(n1);
    v.w = 0.0f;
    lut[e] = v;
}

// ---- Kernel 2: LDS-staged fused resample, 8-wave blocks, interleaved x-pairs ----
// Block: one (b,x) output slice row-group: 16 y x 192 z. Threads (64,8).
// Stage vol[{nx0,nx1}][nymin..nymax][0..191] into LDS as [R][192][2] floats
// (x0/x1 interleaved), then 4 ds_read_b64 per output.
__global__ __launch_bounds__(512, 8) void mimic_acq_lds2_kernel(
    const float* __restrict__ vol,    // [2,192,192,192,1]
    const float4* __restrict__ lut,   // [2*3*192]
    float* __restrict__ out)          // [2,192,192,192,1]
{
    __shared__ float lds[RMAX * 2 * DIM];   // 39936 B -> 4 blocks/CU, 32 waves/CU

    const int tz  = threadIdx.x;            // 0..63  (z lane)
    const int ty  = threadIdx.y;            // 0..7   (one wave per ty)
    const int tid = ty * 64 + tz;
    const int ytile = blockIdx.x;           // 0..11
    const int bx    = blockIdx.y;           // b*192 + x
    const int b  = (bx >= DIM) ? 1 : 0;
    const int x  = bx - b * DIM;
    const int y0t = ytile * 16;

    // x corners (block-uniform)
    const float4 ex = lut[(b * 3 + 0) * DIM + x];
    const float w0x = ex.x, w1x = 1.0f - ex.x;
    const int nx0 = __float_as_int(ex.y), nx1 = __float_as_int(ex.z);

    // y staging range: n0/n1 monotone in y -> [n0(first), n1(last)]
    const float4 eyf = lut[(b * 3 + 1) * DIM + y0t];
    const float4 eyl = lut[(b * 3 + 1) * DIM + y0t + 15];
    const int nymin = __float_as_int(eyf.y);
    const int nymax = __float_as_int(eyl.z);
    const int R = nymax - nymin + 1;        // <= 25 for sr in [1,4)

    const float* vb = vol + (size_t)b * (DIM * DIM * DIM);
    const float* row0 = vb + ((size_t)nx0 * DIM + nymin) * DIM;
    const float* row1 = vb + ((size_t)nx1 * DIM + nymin) * DIM;

    // ---- stage: c indexes float4-quads of 4 z positions per staged y-row ----
    const int C = R * 48;
    for (int c = tid; c < C; c += 512) {
        const int y  = c / 48;
        const int z4 = (c - y * 48) * 4;
        const float4 v0 = *(const float4*)(row0 + y * DIM + z4);
        const float4 v1 = *(const float4*)(row1 + y * DIM + z4);
        float4 qa, qb;
        qa.x = v0.x; qa.y = v1.x; qa.z = v0.y; qa.w = v1.y;
        qb.x = v0.z; qb.y = v1.z; qb.z = v0.w; qb.w = v1.w;
        float4* dst = (float4*)&lds[y * (2 * DIM) + z4 * 2];
        dst[0] = qa;
        dst[1] = qb;
    }
    __syncthreads();

    // z LUT entries for this lane's 3 z positions (pre-scaled to interleaved idx)
    float w0z[3];
    int   zb0[3], zb1[3];
#pragma unroll
    for (int k = 0; k < 3; ++k) {
        const int z = tz + k * 64;
        const float4 ez = lut[(b * 3 + 2) * DIM + z];
        w0z[k] = ez.x;
        zb0[k] = __float_as_int(ez.y) * 2;
        zb1[k] = __float_as_int(ez.z) * 2;
    }

#pragma unroll
    for (int yj = 0; yj < 2; ++yj) {
        const int y = y0t + ty * 2 + yj;
        const float4 ey = lut[(b * 3 + 1) * DIM + y];
        const float w0y = ey.x, w1y = 1.0f - ey.x;
        const int r0 = (__float_as_int(ey.y) - nymin) * (2 * DIM);
        const int r1 = (__float_as_int(ey.z) - nymin) * (2 * DIM);

        const float a00 = w0x * w0y;
        const float a10 = w1x * w0y;
        const float a01 = w0x * w1y;
        const float a11 = w1x * w1y;

        float* ob = out + ((size_t)bx * DIM + y) * DIM + tz;

#pragma unroll
        for (int k = 0; k < 3; ++k) {
            const float2 p00 = *(const float2*)&lds[r0 + zb0[k]];  // {v000, v100}
            const float2 p01 = *(const float2*)&lds[r1 + zb0[k]];  // {v010, v110}
            const float2 p10 = *(const float2*)&lds[r0 + zb1[k]];  // {v001, v101}
            const float2 p11 = *(const float2*)&lds[r1 + zb1[k]];  // {v011, v111}

            const float wz0 = w0z[k];
            const float wz1 = 1.0f - wz0;

            // identical association order to the passing kernel: (a)*(wz)*v
            float acc = 0.0f;
            acc += a00 * wz0 * p00.x;
            acc += a10 * wz0 * p00.y;
            acc += a01 * wz0 * p01.x;
            acc += a11 * wz0 * p01.y;
            acc += a00 * wz1 * p10.x;
            acc += a10 * wz1 * p10.y;
            acc += a01 * wz1 * p11.x;
            acc += a11 * wz1 * p11.y;

            __builtin_nontemporal_store(acc, ob + k * 64);
        }
    }
}

// Fallback (round-1 kernel) in case ws is too small for the LUT.
__global__ __launch_bounds__(256) void mimic_acq_fused_kernel(
    const float* __restrict__ vol,
    const float* __restrict__ sres,
    float* __restrict__ out)
{
    const int z  = blockIdx.x * 64 + threadIdx.x;
    const int y  = blockIdx.y * 4  + threadIdx.y;
    const int bx = blockIdx.z;
    const int b  = (bx >= DIM) ? 1 : 0;
    const int x  = bx - b * DIM;

    const float srx = sres[b * 3 + 0];
    const float sry = sres[b * 3 + 1];
    const float srz = sres[b * 3 + 2];
    const int dsx = (int)(192.0f / srx);
    const int dsy = (int)(192.0f / sry);
    const int dsz = (int)(192.0f / srz);
    const float dsxf = (float)dsx, dsyf = (float)dsy, dszf = (float)dsz;

    const float uzx = 192.0f / dsxf;
    const float uzy = 192.0f / dsyf;
    const float uzz = 192.0f / dszf;

    float lx = (float)x / uzx; lx = fminf(fmaxf(lx, 0.0f), 191.0f);
    float ly = (float)y / uzy; ly = fminf(fmaxf(ly, 0.0f), 191.0f);
    float lz = (float)z / uzz; lz = fminf(fmaxf(lz, 0.0f), 191.0f);

    const float f0x = floorf(lx), f0y = floorf(ly), f0z = floorf(lz);
    const float f1x = fminf(f0x + 1.0f, 191.0f);
    const float f1y = fminf(f0y + 1.0f, 191.0f);
    const float f1z = fminf(f0z + 1.0f, 191.0f);

    const float w0x = f1x - lx, w1x = 1.0f - w0x;
    const float w0y = f1y - ly, w1y = 1.0f - w0y;
    const float w0z = f1z - lz, w1z = 1.0f - w0z;

    const float dzx = dsxf / 192.0f;
    const float dzy = dsyf / 192.0f;
    const float dzz = dszf / 192.0f;

    const int nx0 = nearest_map((int)f0x, dzx), nx1 = nearest_map((int)f1x, dzx);
    const int ny0 = nearest_map((int)f0y, dzy), ny1 = nearest_map((int)f1y, dzy);
    const int nz0 = nearest_map((int)f0z, dzz), nz1 = nearest_map((int)f1z, dzz);

    const float* vb = vol + (size_t)b * (DIM * DIM * DIM);

    float acc = 0.0f;
#pragma unroll
    for (int c = 0; c < 8; ++c) {
        const int xi = (c & 1) ? nx1 : nx0;
        const int yi = (c & 2) ? ny1 : ny0;
        const int zi = (c & 4) ? nz1 : nz0;
        const float w = ((c & 1) ? w1x : w0x)
                      * ((c & 2) ? w1y : w0y)
                      * ((c & 4) ? w1z : w0z);
        acc += w * vb[((size_t)xi * DIM + yi) * DIM + zi];
    }

    out[((size_t)bx * DIM + y) * DIM + z] = acc;
}

extern "C" void kernel_launch(void* const* d_in, const int* in_sizes, int n_in,
                              void* d_out, int out_size, void* d_ws, size_t ws_size,
                              hipStream_t stream) {
    const float* vol  = (const float*)d_in[0];
    const float* sres = (const float*)d_in[1];
    float* out = (float*)d_out;

    const size_t lut_bytes = (size_t)(2 * 3 * DIM) * sizeof(float4);

    if (ws_size >= lut_bytes) {
        float4* lut = (float4*)d_ws;
        hipLaunchKernelGGL(build_lut_kernel, dim3(6), dim3(192), 0, stream, sres, lut);
        dim3 block(64, 8, 1);
        dim3 grid(12, 2 * DIM, 1);   // (ytile, b*192+x)
        hipLaunchKernelGGL(mimic_acq_lds2_kernel, grid, block, 0, stream, vol, lut, out);
    } else {
        dim3 block(64, 4, 1);
        dim3 grid(DIM / 64, DIM / 4, 2 * DIM);
        hipLaunchKernelGGL(mimic_acq_fused_kernel, grid, block, 0, stream, vol, sres, out);
    }
}

// Round 6
// 36.552 us; speedup vs baseline: 3.4621x; 1.0183x over previous
//
#include <hip/hip_runtime.h>

#define DIM 192
#define RMAX 26   // max staged y-rows: span <= 15 + 2*(192/ds) + 1 <= 24 for ds>=48 (sr<4)

typedef float v2f __attribute__((ext_vector_type(2)));

// nearest-resample index map for pass 1 (mid index t -> vol index),
// bit-exact with: clip(round(clip(t / dz, 0, 192)), 0, 191)
__device__ __forceinline__ int nearest_map(int t, float dz) {
    float dl = (float)t / dz;                 // same float div as jnp
    dl = fminf(fmaxf(dl, 0.0f), 192.0f);      // layer clip to [0, inshape]
    float r = rintf(dl);                      // round half-to-even == jnp.round
    r = fminf(r, 191.0f);                     // interp_nearest clip
    return (int)r;
}

// ---- Kernel 1: per-(batch,axis,i) LUT: {w0, n0, n1} (raw indices) ----
__global__ __launch_bounds__(192) void build_lut_kernel(
    const float* __restrict__ sres,   // [2,3]
    float4* __restrict__ lut)         // [2*3*192]
{
    const int e = blockIdx.x * 192 + threadIdx.x;   // e in [0, 1152)
    if (e >= 2 * 3 * DIM) return;
    const int i  = e % DIM;
    const int ba = e / DIM;            // b*3 + axis

    const float sr = sres[ba];
    const int   ds = (int)(192.0f / sr);     // int32 truncation, as astype
    const float dsf = (float)ds;

    // pass-2 trilinear coordinate (exact op order of reference)
    const float uz = 192.0f / dsf;
    float l = (float)i / uz;
    l = fminf(fmaxf(l, 0.0f), 191.0f);
    const float f0 = floorf(l);
    const float f1 = fminf(f0 + 1.0f, 191.0f);
    const float w0 = f1 - l;

    // pass-1 nearest map applied to both corners
    const float dz = dsf / 192.0f;
    const int n0 = nearest_map((int)f0, dz);
    const int n1 = nearest_map((int)f1, dz);

    float4 v;
    v.x = w0;
    v.y = __int_as_float(n0);
    v.z = __int_as_float(n1);
    v.w = 0.0f;
    lut[e] = v;
}

// ---- Kernel 2: LDS-staged fused resample, 8-wave blocks, packed lerp ----
// Block: one (b,x) output slice row-group: 16 y x 192 z. Threads (64,8).
// Stage vol[{nx0,nx1}][nymin..nymax][0..191] into LDS as [R][192] float2
// (x0/x1 interleaved); compute = factored trilinear lerp in packed f32.
__global__ __launch_bounds__(512, 8) void mimic_acq_lds3_kernel(
    const float* __restrict__ vol,    // [2,192,192,192,1]
    const float4* __restrict__ lut,   // [2*3*192]
    float* __restrict__ out)          // [2,192,192,192,1]
{
    __shared__ float lds[RMAX * 2 * DIM];   // 39936 B -> 4 blocks/CU, 32 waves/CU

    const int tz  = threadIdx.x;            // 0..63  (z lane)
    const int ty  = threadIdx.y;            // 0..7   (one wave per ty)
    const int tid = ty * 64 + tz;
    const int ytile = blockIdx.x;           // 0..11
    const int bx    = blockIdx.y;           // b*192 + x
    const int b  = (bx >= DIM) ? 1 : 0;
    const int x  = bx - b * DIM;
    const int y0t = ytile * 16;

    // x corners (block-uniform)
    const float4 ex = lut[(b * 3 + 0) * DIM + x];
    const float w0x = ex.x, w1x = 1.0f - ex.x;
    const int nx0 = __float_as_int(ex.y), nx1 = __float_as_int(ex.z);

    // y staging range: n0/n1 monotone in y -> [n0(first), n1(last)]
    const float4 eyf = lut[(b * 3 + 1) * DIM + y0t];
    const float4 eyl = lut[(b * 3 + 1) * DIM + y0t + 15];
    const int nymin = __float_as_int(eyf.y);
    const int nymax = __float_as_int(eyl.z);
    const int R = nymax - nymin + 1;        // <= 25 for sr in [1,4)

    const float* vb = vol + (size_t)b * (DIM * DIM * DIM);
    const float* row0 = vb + ((size_t)nx0 * DIM + nymin) * DIM;
    const float* row1 = vb + ((size_t)nx1 * DIM + nymin) * DIM;

    // ---- stage: c indexes float4-quads of 4 z positions per staged y-row ----
    const int C = R * 48;
    for (int c = tid; c < C; c += 512) {
        const int y  = c / 48;
        const int z4 = (c - y * 48) * 4;
        const float4 v0 = *(const float4*)(row0 + y * DIM + z4);
        const float4 v1 = *(const float4*)(row1 + y * DIM + z4);
        float4 qa, qb;
        qa.x = v0.x; qa.y = v1.x; qa.z = v0.y; qa.w = v1.y;
        qb.x = v0.z; qb.y = v1.z; qb.z = v0.w; qb.w = v1.w;
        float4* dst = (float4*)&lds[y * (2 * DIM) + z4 * 2];
        dst[0] = qa;
        dst[1] = qb;
    }
    __syncthreads();

    // z LUT entries for this lane's 3 z positions (v2f element indices)
    float w0zk[3];
    int   zz0[3], zz1[3];
#pragma unroll
    for (int k = 0; k < 3; ++k) {
        const int z = tz + k * 64;
        const float4 ez = lut[(b * 3 + 2) * DIM + z];
        w0zk[k] = ez.x;
        zz0[k]  = __float_as_int(ez.y);
        zz1[k]  = __float_as_int(ez.z);
    }

    const v2f* Lp = (const v2f*)lds;

#pragma unroll
    for (int yj = 0; yj < 2; ++yj) {
        const int y = y0t + ty * 2 + yj;
        const float4 ey = lut[(b * 3 + 1) * DIM + y];
        const float w0y = ey.x, w1y = 1.0f - ey.x;
        const int rr0 = (__float_as_int(ey.y) - nymin) * DIM;   // v2f row base
        const int rr1 = (__float_as_int(ey.z) - nymin) * DIM;

        float* ob = out + ((size_t)bx * DIM + y) * DIM + tz;

#pragma unroll
        for (int k = 0; k < 3; ++k) {
            const v2f p00 = Lp[rr0 + zz0[k]];   // {v000, v100}
            const v2f p01 = Lp[rr1 + zz0[k]];   // {v010, v110}
            const v2f p10 = Lp[rr0 + zz1[k]];   // {v001, v101}
            const v2f p11 = Lp[rr1 + zz1[k]];   // {v011, v111}

            const float wz0 = w0zk[k];
            const float wz1 = 1.0f - wz0;

            // factored trilinear lerp (packed over x0/x1):
            const v2f l0 = p00 * wz0 + p10 * wz1;   // z-lerp at y0
            const v2f l1 = p01 * wz0 + p11 * wz1;   // z-lerp at y1
            const v2f m  = l0 * w0y + l1 * w1y;     // y-lerp
            const float r = m.x * w0x + m.y * w1x;  // x-lerp

            __builtin_nontemporal_store(r, ob + k * 64);
        }
    }
}

// Fallback (round-1 kernel) in case ws is too small for the LUT.
__global__ __launch_bounds__(256) void mimic_acq_fused_kernel(
    const float* __restrict__ vol,
    const float* __restrict__ sres,
    float* __restrict__ out)
{
    const int z  = blockIdx.x * 64 + threadIdx.x;
    const int y  = blockIdx.y * 4  + threadIdx.y;
    const int bx = blockIdx.z;
    const int b  = (bx >= DIM) ? 1 : 0;
    const int x  = bx - b * DIM;

    const float srx = sres[b * 3 + 0];
    const float sry = sres[b * 3 + 1];
    const float srz = sres[b * 3 + 2];
    const int dsx = (int)(192.0f / srx);
    const int dsy = (int)(192.0f / sry);
    const int dsz = (int)(192.0f / srz);
    const float dsxf = (float)dsx, dsyf = (float)dsy, dszf = (float)dsz;

    const float uzx = 192.0f / dsxf;
    const float uzy = 192.0f / dsyf;
    const float uzz = 192.0f / dszf;

    float lx = (float)x / uzx; lx = fminf(fmaxf(lx, 0.0f), 191.0f);
    float ly = (float)y / uzy; ly = fminf(fmaxf(ly, 0.0f), 191.0f);
    float lz = (float)z / uzz; lz = fminf(fmaxf(lz, 0.0f), 191.0f);

    const float f0x = floorf(lx), f0y = floorf(ly), f0z = floorf(lz);
    const float f1x = fminf(f0x + 1.0f, 191.0f);
    const float f1y = fminf(f0y + 1.0f, 191.0f);
    const float f1z = fminf(f0z + 1.0f, 191.0f);

    const float w0x = f1x - lx, w1x = 1.0f - w0x;
    const float w0y = f1y - ly, w1y = 1.0f - w0y;
    const float w0z = f1z - lz, w1z = 1.0f - w0z;

    const float dzx = dsxf / 192.0f;
    const float dzy = dsyf / 192.0f;
    const float dzz = dszf / 192.0f;

    const int nx0 = nearest_map((int)f0x, dzx), nx1 = nearest_map((int)f1x, dzx);
    const int ny0 = nearest_map((int)f0y, dzy), ny1 = nearest_map((int)f1y, dzy);
    const int nz0 = nearest_map((int)f0z, dzz), nz1 = nearest_map((int)f1z, dzz);

    const float* vb = vol + (size_t)b * (DIM * DIM * DIM);

    float acc = 0.0f;
#pragma unroll
    for (int c = 0; c < 8; ++c) {
        const int xi = (c & 1) ? nx1 : nx0;
        const int yi = (c & 2) ? ny1 : ny0;
        const int zi = (c & 4) ? nz1 : nz0;
        const float w = ((c & 1) ? w1x : w0x)
                      * ((c & 2) ? w1y : w0y)
                      * ((c & 4) ? w1z : w0z);
        acc += w * vb[((size_t)xi * DIM + yi) * DIM + zi];
    }

    out[((size_t)bx * DIM + y) * DIM + z] = acc;
}

extern "C" void kernel_launch(void* const* d_in, const int* in_sizes, int n_in,
                              void* d_out, int out_size, void* d_ws, size_t ws_size,
                              hipStream_t stream) {
    const float* vol  = (const float*)d_in[0];
    const float* sres = (const float*)d_in[1];
    float* out = (float*)d_out;

    const size_t lut_bytes = (size_t)(2 * 3 * DIM) * sizeof(float4);

    if (ws_size >= lut_bytes) {
        float4* lut = (float4*)d_ws;
        hipLaunchKernelGGL(build_lut_kernel, dim3(6), dim3(192), 0, stream, sres, lut);
        dim3 block(64, 8, 1);
        dim3 grid(12, 2 * DIM, 1);   // (ytile, b*192+x)
        hipLaunchKernelGGL(mimic_acq_lds3_kernel, grid, block, 0, stream, vol, lut, out);
    } else {
        dim3 block(64, 4, 1);
        dim3 grid(DIM / 64, DIM / 4, 2 * DIM);
        hipLaunchKernelGGL(mimic_acq_fused_kernel, grid, block, 0, stream, vol, sres, out);
    }
}

// Round 7
// 30.509 us; speedup vs baseline: 4.1478x; 1.1981x over previous
//
#include <hip/hip_runtime.h>

#define DIM 192
#define RMAX 26   // per-16-row tile staged span <= 25 for ds>=48 (sr<4)

typedef float v2f __attribute__((ext_vector_type(2)));

// nearest-resample index map for pass 1 (mid index t -> vol index),
// bit-exact with: clip(round(clip(t / dz, 0, 192)), 0, 191)
__device__ __forceinline__ int nearest_map(int t, float dz) {
    float dl = (float)t / dz;                 // same float div as jnp
    dl = fminf(fmaxf(dl, 0.0f), 192.0f);      // layer clip to [0, inshape]
    float r = rintf(dl);                      // round half-to-even == jnp.round
    r = fminf(r, 191.0f);                     // interp_nearest clip
    return (int)r;
}

// ---- Kernel 1: per-(batch,axis,i) LUT: {w0, n0, n1} (raw indices) ----
__global__ __launch_bounds__(192) void build_lut_kernel(
    const float* __restrict__ sres,   // [2,3]
    float4* __restrict__ lut)         // [2*3*192]
{
    const int e = blockIdx.x * 192 + threadIdx.x;   // e in [0, 1152)
    if (e >= 2 * 3 * DIM) return;
    const int i  = e % DIM;
    const int ba = e / DIM;            // b*3 + axis

    const float sr = sres[ba];
    const int   ds = (int)(192.0f / sr);     // int32 truncation, as astype
    const float dsf = (float)ds;

    // pass-2 trilinear coordinate (exact op order of reference)
    const float uz = 192.0f / dsf;
    float l = (float)i / uz;
    l = fminf(fmaxf(l, 0.0f), 191.0f);
    const float f0 = floorf(l);
    const float f1 = fminf(f0 + 1.0f, 191.0f);
    const float w0 = f1 - l;

    // pass-1 nearest map applied to both corners
    const float dz = dsf / 192.0f;
    const int n0 = nearest_map((int)f0, dz);
    const int n1 = nearest_map((int)f1, dz);

    float4 v;
    v.x = w0;
    v.y = __int_as_float(n0);
    v.z = __int_as_float(n1);
    v.w = 0.0f;
    lut[e] = v;
}

// ---- Kernel 2: 2-tile pipelined LDS resample, XCD-chunked swizzle ----
// Block: one (b,x), TWO 16-row y-tiles. Threads (64,8).
// stage t0 -> bar -> prefetch t1 to regs -> compute t0 -> bar -> write t1
// -> bar -> compute t1.
__global__ __launch_bounds__(512, 4) void mimic_acq_pipe_kernel(
    const float* __restrict__ vol,    // [2,192,192,192,1]
    const float4* __restrict__ lut,   // [2*3*192]
    float* __restrict__ out)          // [2,192,192,192,1]
{
    __shared__ float lds[RMAX * 2 * DIM];   // 39936 B

    const int tz  = threadIdx.x;            // 0..63  (z lane)
    const int ty  = threadIdx.y;            // 0..7
    const int tid = ty * 64 + tz;

    const int bid = blockIdx.x;             // 0..2303
    const int wg  = (bid & 7) * 288 + (bid >> 3);   // XCD-chunked (2304 = 8*288)
    const int bx  = wg / 6;                 // b*192 + x
    const int tp  = wg % 6;                 // tile-pair -> ytiles 2tp, 2tp+1
    const int b   = (bx >= DIM) ? 1 : 0;
    const int x   = bx - b * DIM;
    const int y0t0 = tp * 32;
    const int y0t1 = y0t0 + 16;

    // x corners (block-uniform)
    const float4 ex = lut[(b * 3 + 0) * DIM + x];
    const float w0x = ex.x, w1x = 1.0f - ex.x;
    const int nx0 = __float_as_int(ex.y), nx1 = __float_as_int(ex.z);

    const float* vb = vol + (size_t)b * (DIM * DIM * DIM);

    // y staging ranges (n0/n1 monotone in y)
    const float4 eyf0 = lut[(b * 3 + 1) * DIM + y0t0];
    const float4 eyl0 = lut[(b * 3 + 1) * DIM + y0t0 + 15];
    const int nymin0 = __float_as_int(eyf0.y);
    const int R0 = __float_as_int(eyl0.z) - nymin0 + 1;

    const float4 eyf1 = lut[(b * 3 + 1) * DIM + y0t1];
    const float4 eyl1 = lut[(b * 3 + 1) * DIM + y0t1 + 15];
    const int nymin1 = __float_as_int(eyf1.y);
    const int R1 = __float_as_int(eyl1.z) - nymin1 + 1;

    // z entries for this lane's 3 z positions (shared by both tiles)
    float w0zk[3];
    int   zz0[3], zz1[3];
#pragma unroll
    for (int k = 0; k < 3; ++k) {
        const float4 ez = lut[(b * 3 + 2) * DIM + tz + k * 64];
        w0zk[k] = ez.x;
        zz0[k]  = __float_as_int(ez.y);
        zz1[k]  = __float_as_int(ez.z);
    }

    // factored trilinear lerp over one tile held in lds
    auto compute = [&](int y0t, int nymin) {
        const v2f* Lp = (const v2f*)lds;
#pragma unroll
        for (int yj = 0; yj < 2; ++yj) {
            const int y = y0t + ty * 2 + yj;
            const float4 ey = lut[(b * 3 + 1) * DIM + y];
            const float w0y = ey.x, w1y = 1.0f - ey.x;
            const int rr0 = (__float_as_int(ey.y) - nymin) * DIM;
            const int rr1 = (__float_as_int(ey.z) - nymin) * DIM;
            float* ob = out + ((size_t)bx * DIM + y) * DIM + tz;
#pragma unroll
            for (int k = 0; k < 3; ++k) {
                const v2f p00 = Lp[rr0 + zz0[k]];   // {v000, v100}
                const v2f p01 = Lp[rr1 + zz0[k]];   // {v010, v110}
                const v2f p10 = Lp[rr0 + zz1[k]];   // {v001, v101}
                const v2f p11 = Lp[rr1 + zz1[k]];   // {v011, v111}
                const float wz0 = w0zk[k];
                const float wz1 = 1.0f - wz0;
                const v2f l0 = p00 * wz0 + p10 * wz1;   // z-lerp at y0
                const v2f l1 = p01 * wz0 + p11 * wz1;   // z-lerp at y1
                const v2f m  = l0 * w0y + l1 * w1y;     // y-lerp
                const float r = m.x * w0x + m.y * w1x;  // x-lerp
                __builtin_nontemporal_store(r, ob + k * 64);
            }
        }
    };

    // ---- stage tile 0 ----
    {
        const float* r0 = vb + ((size_t)nx0 * DIM + nymin0) * DIM;
        const float* r1 = vb + ((size_t)nx1 * DIM + nymin0) * DIM;
        const int C = R0 * 48;
        for (int c = tid; c < C; c += 512) {
            const int yy = c / 48;
            const int z4 = (c - yy * 48) * 4;
            const float4 v0 = *(const float4*)(r0 + yy * DIM + z4);
            const float4 v1 = *(const float4*)(r1 + yy * DIM + z4);
            float4 qa, qb;
            qa.x = v0.x; qa.y = v1.x; qa.z = v0.y; qa.w = v1.y;
            qb.x = v0.z; qb.y = v1.z; qb.z = v0.w; qb.w = v1.w;
            float4* dst = (float4*)&lds[yy * (2 * DIM) + z4 * 2];
            dst[0] = qa;
            dst[1] = qb;
        }
    }
    __syncthreads();

    // ---- prefetch tile 1 to registers (HBM latency hides under compute t0) ----
    const int C1 = R1 * 48;
    const float* r0b = vb + ((size_t)nx0 * DIM + nymin1) * DIM;
    const float* r1b = vb + ((size_t)nx1 * DIM + nymin1) * DIM;
    const int ca = tid, cb = tid + 512, cc = tid + 1024;
    const bool qa_ = ca < C1, qb_ = cb < C1, qc_ = cc < C1;
    float4 pa0, pb0, pa1, pb1, pa2, pb2;
    if (qa_) {
        const int yy = ca / 48, z4 = (ca - yy * 48) * 4;
        pa0 = *(const float4*)(r0b + yy * DIM + z4);
        pb0 = *(const float4*)(r1b + yy * DIM + z4);
    }
    if (qb_) {
        const int yy = cb / 48, z4 = (cb - yy * 48) * 4;
        pa1 = *(const float4*)(r0b + yy * DIM + z4);
        pb1 = *(const float4*)(r1b + yy * DIM + z4);
    }
    if (qc_) {
        const int yy = cc / 48, z4 = (cc - yy * 48) * 4;
        pa2 = *(const float4*)(r0b + yy * DIM + z4);
        pb2 = *(const float4*)(r1b + yy * DIM + z4);
    }

    // ---- compute tile 0 (overlaps tile-1 loads) ----
    compute(y0t0, nymin0);

    __syncthreads();   // everyone done reading buf

    // ---- write tile 1 into lds ----
    if (qa_) {
        const int yy = ca / 48, z4 = (ca - yy * 48) * 4;
        float4 qa, qb;
        qa.x = pa0.x; qa.y = pb0.x; qa.z = pa0.y; qa.w = pb0.y;
        qb.x = pa0.z; qb.y = pb0.z; qb.z = pa0.w; qb.w = pb0.w;
        float4* dst = (float4*)&lds[yy * (2 * DIM) + z4 * 2];
        dst[0] = qa; dst[1] = qb;
    }
    if (qb_) {
        const int yy = cb / 48, z4 = (cb - yy * 48) * 4;
        float4 qa, qb;
        qa.x = pa1.x; qa.y = pb1.x; qa.z = pa1.y; qa.w = pb1.y;
        qb.x = pa1.z; qb.y = pb1.z; qb.z = pa1.w; qb.w = pb1.w;
        float4* dst = (float4*)&lds[yy * (2 * DIM) + z4 * 2];
        dst[0] = qa; dst[1] = qb;
    }
    if (qc_) {
        const int yy = cc / 48, z4 = (cc - yy * 48) * 4;
        float4 qa, qb;
        qa.x = pa2.x; qa.y = pb2.x; qa.z = pa2.y; qa.w = pb2.y;
        qb.x = pa2.z; qb.y = pb2.z; qb.z = pa2.w; qb.w = pb2.w;
        float4* dst = (float4*)&lds[yy * (2 * DIM) + z4 * 2];
        dst[0] = qa; dst[1] = qb;
    }
    __syncthreads();

    // ---- compute tile 1 ----
    compute(y0t1, nymin1);
}

// Fallback (round-1 kernel) in case ws is too small for the LUT.
__global__ __launch_bounds__(256) void mimic_acq_fused_kernel(
    const float* __restrict__ vol,
    const float* __restrict__ sres,
    float* __restrict__ out)
{
    const int z  = blockIdx.x * 64 + threadIdx.x;
    const int y  = blockIdx.y * 4  + threadIdx.y;
    const int bx = blockIdx.z;
    const int b  = (bx >= DIM) ? 1 : 0;
    const int x  = bx - b * DIM;

    const float srx = sres[b * 3 + 0];
    const float sry = sres[b * 3 + 1];
    const float srz = sres[b * 3 + 2];
    const int dsx = (int)(192.0f / srx);
    const int dsy = (int)(192.0f / sry);
    const int dsz = (int)(192.0f / srz);
    const float dsxf = (float)dsx, dsyf = (float)dsy, dszf = (float)dsz;

    const float uzx = 192.0f / dsxf;
    const float uzy = 192.0f / dsyf;
    const float uzz = 192.0f / dszf;

    float lx = (float)x / uzx; lx = fminf(fmaxf(lx, 0.0f), 191.0f);
    float ly = (float)y / uzy; ly = fminf(fmaxf(ly, 0.0f), 191.0f);
    float lz = (float)z / uzz; lz = fminf(fmaxf(lz, 0.0f), 191.0f);

    const float f0x = floorf(lx), f0y = floorf(ly), f0z = floorf(lz);
    const float f1x = fminf(f0x + 1.0f, 191.0f);
    const float f1y = fminf(f0y + 1.0f, 191.0f);
    const float f1z = fminf(f0z + 1.0f, 191.0f);

    const float w0x = f1x - lx, w1x = 1.0f - w0x;
    const float w0y = f1y - ly, w1y = 1.0f - w0y;
    const float w0z = f1z - lz, w1z = 1.0f - w0z;

    const float dzx = dsxf / 192.0f;
    const float dzy = dsyf / 192.0f;
    const float dzz = dszf / 192.0f;

    const int nx0 = nearest_map((int)f0x, dzx), nx1 = nearest_map((int)f1x, dzx);
    const int ny0 = nearest_map((int)f0y, dzy), ny1 = nearest_map((int)f1y, dzy);
    const int nz0 = nearest_map((int)f0z, dzz), nz1 = nearest_map((int)f1z, dzz);

    const float* vb = vol + (size_t)b * (DIM * DIM * DIM);

    float acc = 0.0f;
#pragma unroll
    for (int c = 0; c < 8; ++c) {
        const int xi = (c & 1) ? nx1 : nx0;
        const int yi = (c & 2) ? ny1 : ny0;
        const int zi = (c & 4) ? nz1 : nz0;
        const float w = ((c & 1) ? w1x : w0x)
                      * ((c & 2) ? w1y : w0y)
                      * ((c & 4) ? w1z : w0z);
        acc += w * vb[((size_t)xi * DIM + yi) * DIM + zi];
    }

    out[((size_t)bx * DIM + y) * DIM + z] = acc;
}

extern "C" void kernel_launch(void* const* d_in, const int* in_sizes, int n_in,
                              void* d_out, int out_size, void* d_ws, size_t ws_size,
                              hipStream_t stream) {
    const float* vol  = (const float*)d_in[0];
    const float* sres = (const float*)d_in[1];
    float* out = (float*)d_out;

    const size_t lut_bytes = (size_t)(2 * 3 * DIM) * sizeof(float4);

    if (ws_size >= lut_bytes) {
        float4* lut = (float4*)d_ws;
        hipLaunchKernelGGL(build_lut_kernel, dim3(6), dim3(192), 0, stream, sres, lut);
        dim3 block(64, 8, 1);
        dim3 grid(2304, 1, 1);   // (b*192+x) * 6 tile-pairs, XCD-swizzled in-kernel
        hipLaunchKernelGGL(mimic_acq_pipe_kernel, grid, block, 0, stream, vol, lut, out);
    } else {
        dim3 block(64, 4, 1);
        dim3 grid(DIM / 64, DIM / 4, 2 * DIM);
        hipLaunchKernelGGL(mimic_acq_fused_kernel, grid, block, 0, stream, vol, sres, out);
    }
}

// Round 8
// 29.702 us; speedup vs baseline: 4.2605x; 1.0272x over previous
//
#include <hip/hip_runtime.h>
#include <hip/hip_fp16.h>

#define DIM 192
#define RMAX 26   // per-16-row tile staged span <= 25 for ds>=48 (sr<4)

typedef float v2f __attribute__((ext_vector_type(2)));

// nearest-resample index map for pass 1 (mid index t -> vol index),
// bit-exact with: clip(round(clip(t / dz, 0, 192)), 0, 191)
__device__ __forceinline__ int nearest_map(int t, float dz) {
    float dl = (float)t / dz;                 // same float div as jnp
    dl = fminf(fmaxf(dl, 0.0f), 192.0f);      // layer clip to [0, inshape]
    float r = rintf(dl);                      // round half-to-even == jnp.round
    r = fminf(r, 191.0f);                     // interp_nearest clip
    return (int)r;
}

// ---- Kernel 1: per-(batch,axis,i) LUT: {w0, n0, n1} (raw indices) ----
__global__ __launch_bounds__(192) void build_lut_kernel(
    const float* __restrict__ sres,   // [2,3]
    float4* __restrict__ lut)         // [2*3*192]
{
    const int e = blockIdx.x * 192 + threadIdx.x;   // e in [0, 1152)
    if (e >= 2 * 3 * DIM) return;
    const int i  = e % DIM;
    const int ba = e / DIM;            // b*3 + axis

    const float sr = sres[ba];
    const int   ds = (int)(192.0f / sr);     // int32 truncation, as astype
    const float dsf = (float)ds;

    // pass-2 trilinear coordinate (exact op order of reference)
    const float uz = 192.0f / dsf;
    float l = (float)i / uz;
    l = fminf(fmaxf(l, 0.0f), 191.0f);
    const float f0 = floorf(l);
    const float f1 = fminf(f0 + 1.0f, 191.0f);
    const float w0 = f1 - l;

    // pass-1 nearest map applied to both corners
    const float dz = dsf / 192.0f;
    const int n0 = nearest_map((int)f0, dz);
    const int n1 = nearest_map((int)f1, dz);

    float4 v;
    v.x = w0;
    v.y = __int_as_float(n0);
    v.z = __int_as_float(n1);
    v.w = 0.0f;
    lut[e] = v;
}

__device__ __forceinline__ unsigned int pack_h2(float a, float b) {
    __half2 h = __floats2half2_rn(a, b);
    return *reinterpret_cast<unsigned int*>(&h);
}

__device__ __forceinline__ v2f unpack_h2(unsigned int u) {
    __half2 h = *reinterpret_cast<__half2*>(&u);
    float2 f = __half22float2(h);
    v2f r; r.x = f.x; r.y = f.y;
    return r;
}

// ---- Kernel 2: 2-tile pipelined LDS resample, fp16-pair LDS, XCD swizzle ----
// Block: one (b,x), TWO 16-row y-tiles. Threads (64,8).
// LDS layout: u32[y][z] = half2{vol[x0], vol[x1]} -> 19968 B.
__global__ __launch_bounds__(512, 8) void mimic_acq_pipe_h_kernel(
    const float* __restrict__ vol,    // [2,192,192,192,1]
    const float4* __restrict__ lut,   // [2*3*192]
    float* __restrict__ out)          // [2,192,192,192,1]
{
    __shared__ unsigned int lds[RMAX * DIM];   // 19968 B

    const int tz  = threadIdx.x;            // 0..63  (z lane)
    const int ty  = threadIdx.y;            // 0..7
    const int tid = ty * 64 + tz;

    const int bid = blockIdx.x;             // 0..2303
    const int wg  = (bid & 7) * 288 + (bid >> 3);   // XCD-chunked (2304 = 8*288)
    const int bx  = wg / 6;                 // b*192 + x
    const int tp  = wg % 6;                 // tile-pair -> ytiles 2tp, 2tp+1
    const int b   = (bx >= DIM) ? 1 : 0;
    const int x   = bx - b * DIM;
    const int y0t0 = tp * 32;
    const int y0t1 = y0t0 + 16;

    // x corners (block-uniform)
    const float4 ex = lut[(b * 3 + 0) * DIM + x];
    const float w0x = ex.x, w1x = 1.0f - ex.x;
    const int nx0 = __float_as_int(ex.y), nx1 = __float_as_int(ex.z);

    const float* vb = vol + (size_t)b * (DIM * DIM * DIM);

    // y staging ranges (n0/n1 monotone in y)
    const float4 eyf0 = lut[(b * 3 + 1) * DIM + y0t0];
    const float4 eyl0 = lut[(b * 3 + 1) * DIM + y0t0 + 15];
    const int nymin0 = __float_as_int(eyf0.y);
    const int R0 = __float_as_int(eyl0.z) - nymin0 + 1;

    const float4 eyf1 = lut[(b * 3 + 1) * DIM + y0t1];
    const float4 eyl1 = lut[(b * 3 + 1) * DIM + y0t1 + 15];
    const int nymin1 = __float_as_int(eyf1.y);
    const int R1 = __float_as_int(eyl1.z) - nymin1 + 1;

    // z entries for this lane's 3 z positions (shared by both tiles)
    float w0zk[3];
    int   zz0[3], zz1[3];
#pragma unroll
    for (int k = 0; k < 3; ++k) {
        const float4 ez = lut[(b * 3 + 2) * DIM + tz + k * 64];
        w0zk[k] = ez.x;
        zz0[k]  = __float_as_int(ez.y);
        zz1[k]  = __float_as_int(ez.z);
    }

    // factored trilinear lerp over one tile held in lds
    auto compute = [&](int y0t, int nymin) {
#pragma unroll
        for (int yj = 0; yj < 2; ++yj) {
            const int y = y0t + ty * 2 + yj;
            const float4 ey = lut[(b * 3 + 1) * DIM + y];
            const float w0y = ey.x, w1y = 1.0f - ey.x;
            const int rr0 = (__float_as_int(ey.y) - nymin) * DIM;
            const int rr1 = (__float_as_int(ey.z) - nymin) * DIM;
            float* ob = out + ((size_t)bx * DIM + y) * DIM + tz;
#pragma unroll
            for (int k = 0; k < 3; ++k) {
                const v2f p00 = unpack_h2(lds[rr0 + zz0[k]]);   // {v000, v100}
                const v2f p01 = unpack_h2(lds[rr1 + zz0[k]]);   // {v010, v110}
                const v2f p10 = unpack_h2(lds[rr0 + zz1[k]]);   // {v001, v101}
                const v2f p11 = unpack_h2(lds[rr1 + zz1[k]]);   // {v011, v111}
                const float wz0 = w0zk[k];
                const float wz1 = 1.0f - wz0;
                const v2f l0 = p00 * wz0 + p10 * wz1;   // z-lerp at y0
                const v2f l1 = p01 * wz0 + p11 * wz1;   // z-lerp at y1
                const v2f m  = l0 * w0y + l1 * w1y;     // y-lerp
                const float r = m.x * w0x + m.y * w1x;  // x-lerp
                __builtin_nontemporal_store(r, ob + k * 64);
            }
        }
    };

    // ---- stage tile 0 (load f32, pack to half2 pairs) ----
    {
        const float* r0 = vb + ((size_t)nx0 * DIM + nymin0) * DIM;
        const float* r1 = vb + ((size_t)nx1 * DIM + nymin0) * DIM;
        const int C = R0 * 48;
        for (int c = tid; c < C; c += 512) {
            const int yy = c / 48;
            const int z4 = (c - yy * 48) * 4;
            const float4 v0 = *(const float4*)(r0 + yy * DIM + z4);
            const float4 v1 = *(const float4*)(r1 + yy * DIM + z4);
            uint4 q;
            q.x = pack_h2(v0.x, v1.x);
            q.y = pack_h2(v0.y, v1.y);
            q.z = pack_h2(v0.z, v1.z);
            q.w = pack_h2(v0.w, v1.w);
            *(uint4*)&lds[yy * DIM + z4] = q;
        }
    }
    __syncthreads();

    // ---- prefetch tile 1, pack to registers (HBM latency hides under t0) ----
    const int C1 = R1 * 48;
    const float* r0b = vb + ((size_t)nx0 * DIM + nymin1) * DIM;
    const float* r1b = vb + ((size_t)nx1 * DIM + nymin1) * DIM;
    const int ca = tid, cb = tid + 512, cc = tid + 1024;
    const bool qa_ = ca < C1, qb_ = cb < C1, qc_ = cc < C1;
    uint4 pq0, pq1, pq2;
    if (qa_) {
        const int yy = ca / 48, z4 = (ca - yy * 48) * 4;
        const float4 v0 = *(const float4*)(r0b + yy * DIM + z4);
        const float4 v1 = *(const float4*)(r1b + yy * DIM + z4);
        pq0.x = pack_h2(v0.x, v1.x); pq0.y = pack_h2(v0.y, v1.y);
        pq0.z = pack_h2(v0.z, v1.z); pq0.w = pack_h2(v0.w, v1.w);
    }
    if (qb_) {
        const int yy = cb / 48, z4 = (cb - yy * 48) * 4;
        const float4 v0 = *(const float4*)(r0b + yy * DIM + z4);
        const float4 v1 = *(const float4*)(r1b + yy * DIM + z4);
        pq1.x = pack_h2(v0.x, v1.x); pq1.y = pack_h2(v0.y, v1.y);
        pq1.z = pack_h2(v0.z, v1.z); pq1.w = pack_h2(v0.w, v1.w);
    }
    if (qc_) {
        const int yy = cc / 48, z4 = (cc - yy * 48) * 4;
        const float4 v0 = *(const float4*)(r0b + yy * DIM + z4);
        const float4 v1 = *(const float4*)(r1b + yy * DIM + z4);
        pq2.x = pack_h2(v0.x, v1.x); pq2.y = pack_h2(v0.y, v1.y);
        pq2.z = pack_h2(v0.z, v1.z); pq2.w = pack_h2(v0.w, v1.w);
    }

    // ---- compute tile 0 (overlaps tile-1 loads) ----
    compute(y0t0, nymin0);

    __syncthreads();   // everyone done reading buf

    // ---- write tile 1 into lds ----
    if (qa_) {
        const int yy = ca / 48, z4 = (ca - yy * 48) * 4;
        *(uint4*)&lds[yy * DIM + z4] = pq0;
    }
    if (qb_) {
        const int yy = cb / 48, z4 = (cb - yy * 48) * 4;
        *(uint4*)&lds[yy * DIM + z4] = pq1;
    }
    if (qc_) {
        const int yy = cc / 48, z4 = (cc - yy * 48) * 4;
        *(uint4*)&lds[yy * DIM + z4] = pq2;
    }
    __syncthreads();

    // ---- compute tile 1 ----
    compute(y0t1, nymin1);
}

// Fallback (round-1 kernel) in case ws is too small for the LUT.
__global__ __launch_bounds__(256) void mimic_acq_fused_kernel(
    const float* __restrict__ vol,
    const float* __restrict__ sres,
    float* __restrict__ out)
{
    const int z  = blockIdx.x * 64 + threadIdx.x;
    const int y  = blockIdx.y * 4  + threadIdx.y;
    const int bx = blockIdx.z;
    const int b  = (bx >= DIM) ? 1 : 0;
    const int x  = bx - b * DIM;

    const float srx = sres[b * 3 + 0];
    const float sry = sres[b * 3 + 1];
    const float srz = sres[b * 3 + 2];
    const int dsx = (int)(192.0f / srx);
    const int dsy = (int)(192.0f / sry);
    const int dsz = (int)(192.0f / srz);
    const float dsxf = (float)dsx, dsyf = (float)dsy, dszf = (float)dsz;

    const float uzx = 192.0f / dsxf;
    const float uzy = 192.0f / dsyf;
    const float uzz = 192.0f / dszf;

    float lx = (float)x / uzx; lx = fminf(fmaxf(lx, 0.0f), 191.0f);
    float ly = (float)y / uzy; ly = fminf(fmaxf(ly, 0.0f), 191.0f);
    float lz = (float)z / uzz; lz = fminf(fmaxf(lz, 0.0f), 191.0f);

    const float f0x = floorf(lx), f0y = floorf(ly), f0z = floorf(lz);
    const float f1x = fminf(f0x + 1.0f, 191.0f);
    const float f1y = fminf(f0y + 1.0f, 191.0f);
    const float f1z = fminf(f0z + 1.0f, 191.0f);

    const float w0x = f1x - lx, w1x = 1.0f - w0x;
    const float w0y = f1y - ly, w1y = 1.0f - w0y;
    const float w0z = f1z - lz, w1z = 1.0f - w0z;

    const float dzx = dsxf / 192.0f;
    const float dzy = dsyf / 192.0f;
    const float dzz = dszf / 192.0f;

    const int nx0 = nearest_map((int)f0x, dzx), nx1 = nearest_map((int)f1x, dzx);
    const int ny0 = nearest_map((int)f0y, dzy), ny1 = nearest_map((int)f1y, dzy);
    const int nz0 = nearest_map((int)f0z, dzz), nz1 = nearest_map((int)f1z, dzz);

    const float* vb = vol + (size_t)b * (DIM * DIM * DIM);

    float acc = 0.0f;
#pragma unroll
    for (int c = 0; c < 8; ++c) {
        const int xi = (c & 1) ? nx1 : nx0;
        const int yi = (c & 2) ? ny1 : ny0;
        const int zi = (c & 4) ? nz1 : nz0;
        const float w = ((c & 1) ? w1x : w0x)
                      * ((c & 2) ? w1y : w0y)
                      * ((c & 4) ? w1z : w0z);
        acc += w * vb[((size_t)xi * DIM + yi) * DIM + zi];
    }

    out[((size_t)bx * DIM + y) * DIM + z] = acc;
}

extern "C" void kernel_launch(void* const* d_in, const int* in_sizes, int n_in,
                              void* d_out, int out_size, void* d_ws, size_t ws_size,
                              hipStream_t stream) {
    const float* vol  = (const float*)d_in[0];
    const float* sres = (const float*)d_in[1];
    float* out = (float*)d_out;

    const size_t lut_bytes = (size_t)(2 * 3 * DIM) * sizeof(float4);

    if (ws_size >= lut_bytes) {
        float4* lut = (float4*)d_ws;
        hipLaunchKernelGGL(build_lut_kernel, dim3(6), dim3(192), 0, stream, sres, lut);
        dim3 block(64, 8, 1);
        dim3 grid(2304, 1, 1);   // (b*192+x) * 6 tile-pairs, XCD-swizzled in-kernel
        hipLaunchKernelGGL(mimic_acq_pipe_h_kernel, grid, block, 0, stream, vol, lut, out);
    } else {
        dim3 block(64, 4, 1);
        dim3 grid(DIM / 64, DIM / 4, 2 * DIM);
        hipLaunchKernelGGL(mimic_acq_fused_kernel, grid, block, 0, stream, vol, sres, out);
    }
}

// Round 9
// 28.892 us; speedup vs baseline: 4.3799x; 1.0280x over previous
//
#include <hip/hip_runtime.h>
#include <hip/hip_fp16.h>

#define DIM 192
#define RMAX 26   // per-16-row tile staged span <= 25 for ds>=48 (sr<4)

typedef float v2f __attribute__((ext_vector_type(2)));

// nearest-resample index map for pass 1 (mid index t -> vol index),
// bit-exact with: clip(round(clip(t / dz, 0, 192)), 0, 191)
__device__ __forceinline__ int nearest_map(int t, float dz) {
    float dl = (float)t / dz;                 // same float div as jnp
    dl = fminf(fmaxf(dl, 0.0f), 192.0f);      // layer clip to [0, inshape]
    float r = rintf(dl);                      // round half-to-even == jnp.round
    r = fminf(r, 191.0f);                     // interp_nearest clip
    return (int)r;
}

// ---- Kernel 1: per-(batch,axis,i) LUT: {w0, n0, n1} (raw indices) ----
__global__ __launch_bounds__(192) void build_lut_kernel(
    const float* __restrict__ sres,   // [2,3]
    float4* __restrict__ lut)         // [2*3*192]
{
    const int e = blockIdx.x * 192 + threadIdx.x;   // e in [0, 1152)
    if (e >= 2 * 3 * DIM) return;
    const int i  = e % DIM;
    const int ba = e / DIM;            // b*3 + axis

    const float sr = sres[ba];
    const int   ds = (int)(192.0f / sr);     // int32 truncation, as astype
    const float dsf = (float)ds;

    // pass-2 trilinear coordinate (exact op order of reference)
    const float uz = 192.0f / dsf;
    float l = (float)i / uz;
    l = fminf(fmaxf(l, 0.0f), 191.0f);
    const float f0 = floorf(l);
    const float f1 = fminf(f0 + 1.0f, 191.0f);
    const float w0 = f1 - l;

    // pass-1 nearest map applied to both corners
    const float dz = dsf / 192.0f;
    const int n0 = nearest_map((int)f0, dz);
    const int n1 = nearest_map((int)f1, dz);

    float4 v;
    v.x = w0;
    v.y = __int_as_float(n0);
    v.z = __int_as_float(n1);
    v.w = 0.0f;
    lut[e] = v;
}

__device__ __forceinline__ unsigned int pack_h2(float a, float b) {
    __half2 h = __floats2half2_rn(a, b);
    return *reinterpret_cast<unsigned int*>(&h);
}

__device__ __forceinline__ v2f unpack_h2(unsigned int u) {
    __half2 h = *reinterpret_cast<__half2*>(&u);
    float2 f = __half22float2(h);
    v2f r; r.x = f.x; r.y = f.y;
    return r;
}

// ---- Kernel 2: small-block LDS resample, fp16-pair LDS, XCD swizzle ----
// Block: one (b,x), ONE 16-row y-tile, 256 threads (4 waves).
// 19.97 KB LDS + <=64 VGPR -> 8 independent blocks/CU = 32 waves/CU;
// stage-phase and compute-phase blocks overlap across the CU.
__global__ __launch_bounds__(256, 8) void mimic_acq_sm_kernel(
    const float* __restrict__ vol,    // [2,192,192,192,1]
    const float4* __restrict__ lut,   // [2*3*192]
    float* __restrict__ out)          // [2,192,192,192,1]
{
    __shared__ unsigned int lds[RMAX * DIM];   // 19968 B

    const int tz  = threadIdx.x;            // 0..63  (z lane)
    const int ty  = threadIdx.y;            // 0..3
    const int tid = ty * 64 + tz;

    const int bid = blockIdx.x;             // 0..4607
    const int wg  = (bid & 7) * 576 + (bid >> 3);   // XCD-chunked (4608 = 8*576)
    const int bx  = wg / 12;                // b*192 + x
    const int tile = wg % 12;               // ytile
    const int b   = (bx >= DIM) ? 1 : 0;
    const int x   = bx - b * DIM;
    const int y0t = tile * 16;

    // x corners (block-uniform)
    const float4 ex = lut[(b * 3 + 0) * DIM + x];
    const float w0x = ex.x, w1x = 1.0f - ex.x;
    const int nx0 = __float_as_int(ex.y), nx1 = __float_as_int(ex.z);

    const float* vb = vol + (size_t)b * (DIM * DIM * DIM);

    // y staging range (n0/n1 monotone in y)
    const float4 eyf = lut[(b * 3 + 1) * DIM + y0t];
    const float4 eyl = lut[(b * 3 + 1) * DIM + y0t + 15];
    const int nymin = __float_as_int(eyf.y);
    const int R = __float_as_int(eyl.z) - nymin + 1;   // <= 25

    // ---- stage (load f32 pairs, pack to half2) ----
    {
        const float* r0 = vb + ((size_t)nx0 * DIM + nymin) * DIM;
        const float* r1 = vb + ((size_t)nx1 * DIM + nymin) * DIM;
        const int C = R * 48;
        for (int c = tid; c < C; c += 256) {
            const int yy = c / 48;
            const int z4 = (c - yy * 48) * 4;
            const float4 v0 = *(const float4*)(r0 + yy * DIM + z4);
            const float4 v1 = *(const float4*)(r1 + yy * DIM + z4);
            uint4 q;
            q.x = pack_h2(v0.x, v1.x);
            q.y = pack_h2(v0.y, v1.y);
            q.z = pack_h2(v0.z, v1.z);
            q.w = pack_h2(v0.w, v1.w);
            *(uint4*)&lds[yy * DIM + z4] = q;
        }
    }

    // z entries for this lane's 3 z positions (load while staging in flight)
    float w0zk[3];
    int   zz0[3], zz1[3];
#pragma unroll
    for (int k = 0; k < 3; ++k) {
        const float4 ez = lut[(b * 3 + 2) * DIM + tz + k * 64];
        w0zk[k] = ez.x;
        zz0[k]  = __float_as_int(ez.y);
        zz1[k]  = __float_as_int(ez.z);
    }

    __syncthreads();

    // ---- compute: 4 y rows x 3 z per thread ----
#pragma unroll
    for (int yj = 0; yj < 4; ++yj) {
        const int y = y0t + ty * 4 + yj;
        const float4 ey = lut[(b * 3 + 1) * DIM + y];
        const float w0y = ey.x, w1y = 1.0f - ey.x;
        const int rr0 = (__float_as_int(ey.y) - nymin) * DIM;
        const int rr1 = (__float_as_int(ey.z) - nymin) * DIM;
        float* ob = out + ((size_t)bx * DIM + y) * DIM + tz;
#pragma unroll
        for (int k = 0; k < 3; ++k) {
            const v2f p00 = unpack_h2(lds[rr0 + zz0[k]]);   // {v000, v100}
            const v2f p01 = unpack_h2(lds[rr1 + zz0[k]]);   // {v010, v110}
            const v2f p10 = unpack_h2(lds[rr0 + zz1[k]]);   // {v001, v101}
            const v2f p11 = unpack_h2(lds[rr1 + zz1[k]]);   // {v011, v111}
            const float wz0 = w0zk[k];
            const float wz1 = 1.0f - wz0;
            const v2f l0 = p00 * wz0 + p10 * wz1;   // z-lerp at y0
            const v2f l1 = p01 * wz0 + p11 * wz1;   // z-lerp at y1
            const v2f m  = l0 * w0y + l1 * w1y;     // y-lerp
            const float r = m.x * w0x + m.y * w1x;  // x-lerp
            __builtin_nontemporal_store(r, ob + k * 64);
        }
    }
}

// Fallback (round-1 kernel) in case ws is too small for the LUT.
__global__ __launch_bounds__(256) void mimic_acq_fused_kernel(
    const float* __restrict__ vol,
    const float* __restrict__ sres,
    float* __restrict__ out)
{
    const int z  = blockIdx.x * 64 + threadIdx.x;
    const int y  = blockIdx.y * 4  + threadIdx.y;
    const int bx = blockIdx.z;
    const int b  = (bx >= DIM) ? 1 : 0;
    const int x  = bx - b * DIM;

    const float srx = sres[b * 3 + 0];
    const float sry = sres[b * 3 + 1];
    const float srz = sres[b * 3 + 2];
    const int dsx = (int)(192.0f / srx);
    const int dsy = (int)(192.0f / sry);
    const int dsz = (int)(192.0f / srz);
    const float dsxf = (float)dsx, dsyf = (float)dsy, dszf = (float)dsz;

    const float uzx = 192.0f / dsxf;
    const float uzy = 192.0f / dsyf;
    const float uzz = 192.0f / dszf;

    float lx = (float)x / uzx; lx = fminf(fmaxf(lx, 0.0f), 191.0f);
    float ly = (float)y / uzy; ly = fminf(fmaxf(ly, 0.0f), 191.0f);
    float lz = (float)z / uzz; lz = fminf(fmaxf(lz, 0.0f), 191.0f);

    const float f0x = floorf(lx), f0y = floorf(ly), f0z = floorf(lz);
    const float f1x = fminf(f0x + 1.0f, 191.0f);
    const float f1y = fminf(f0y + 1.0f, 191.0f);
    const float f1z = fminf(f0z + 1.0f, 191.0f);

    const float w0x = f1x - lx, w1x = 1.0f - w0x;
    const float w0y = f1y - ly, w1y = 1.0f - w0y;
    const float w0z = f1z - lz, w1z = 1.0f - w0z;

    const float dzx = dsxf / 192.0f;
    const float dzy = dsyf / 192.0f;
    const float dzz = dszf / 192.0f;

    const int nx0 = nearest_map((int)f0x, dzx), nx1 = nearest_map((int)f1x, dzx);
    const int ny0 = nearest_map((int)f0y, dzy), ny1 = nearest_map((int)f1y, dzy);
    const int nz0 = nearest_map((int)f0z, dzz), nz1 = nearest_map((int)f1z, dzz);

    const float* vb = vol + (size_t)b * (DIM * DIM * DIM);

    float acc = 0.0f;
#pragma unroll
    for (int c = 0; c < 8; ++c) {
        const int xi = (c & 1) ? nx1 : nx0;
        const int yi = (c & 2) ? ny1 : ny0;
        const int zi = (c & 4) ? nz1 : nz0;
        const float w = ((c & 1) ? w1x : w0x)
                      * ((c & 2) ? w1y : w0y)
                      * ((c & 4) ? w1z : w0z);
        acc += w * vb[((size_t)xi * DIM + yi) * DIM + zi];
    }

    out[((size_t)bx * DIM + y) * DIM + z] = acc;
}

extern "C" void kernel_launch(void* const* d_in, const int* in_sizes, int n_in,
                              void* d_out, int out_size, void* d_ws, size_t ws_size,
                              hipStream_t stream) {
    const float* vol  = (const float*)d_in[0];
    const float* sres = (const float*)d_in[1];
    float* out = (float*)d_out;

    const size_t lut_bytes = (size_t)(2 * 3 * DIM) * sizeof(float4);

    if (ws_size >= lut_bytes) {
        float4* lut = (float4*)d_ws;
        hipLaunchKernelGGL(build_lut_kernel, dim3(6), dim3(192), 0, stream, sres, lut);
        dim3 block(64, 4, 1);
        dim3 grid(4608, 1, 1);   // (b*192+x) * 12 ytiles, XCD-swizzled in-kernel
        hipLaunchKernelGGL(mimic_acq_sm_kernel, grid, block, 0, stream, vol, lut, out);
    } else {
        dim3 block(64, 4, 1);
        dim3 grid(DIM / 64, DIM / 4, 2 * DIM);
        hipLaunchKernelGGL(mimic_acq_fused_kernel, grid, block, 0, stream, vol, sres, out);
    }
}